// Round 4
// baseline (225.373 us; speedup 1.0000x reference)
//
#include <hip/hip_runtime.h>

typedef __bf16 bfvec8 __attribute__((ext_vector_type(8)));
typedef float f32x4 __attribute__((ext_vector_type(4)));
typedef unsigned short u16x8 __attribute__((ext_vector_type(8)));
typedef unsigned int u32;

constexpr int C_IN = 128, Wd = 56, Hd = 56, HW = 3136, K_OUT = 256, N_IMG = 32;
constexpr int KKTOT = 1152;      // 128*9
constexpr int WP = 58;           // padded H/W
constexpr size_t XP_ELEMS = (size_t)N_IMG * WP * WP * C_IN;   // 13,776,896
constexpr size_t XP_BYTES = XP_ELEMS * 2;                     // 27,553,792
constexpr size_t WT_ELEMS = (size_t)9 * 4 * 2 * 128 * 32;     // 294,912

// prep-kernel grid partition
constexpr int HALO_BLKS = 456;    // 32 n * 228 halo px * 16 vec8 / 256 thr
constexpr int WT_BLKS   = 1152;   // 294912 / 256
constexpr int XPOSE_BLKS = N_IMG * Hd;   // 1792
constexpr int PREP_GRID = HALO_BLKS + WT_BLKS + XPOSE_BLKS;   // 3400

__device__ inline unsigned short f2bf(float f) {
    union { float f; unsigned u; } v; v.f = f;
    unsigned u = v.u;
    u += 0x7fffu + ((u >> 16) & 1u);   // round-to-nearest-even
    return (unsigned short)(u >> 16);
}

__device__ inline void gld16(const void* g, void* l) {
    __builtin_amdgcn_global_load_lds(
        (const __attribute__((address_space(1))) u32*)g,
        (__attribute__((address_space(3))) u32*)l, 16, 0, 0);
}

// compiler memory fence (no instruction) — pins LDS/global ops vs barriers
#define CFENCE() asm volatile("" ::: "memory")

// ---- Fused pre-pass: halo-zero + weight xform + NCHW->NHWC transpose ------
// Replaces hipMemsetAsync + wxform + xpose (3 dispatches -> 1).
__global__ __launch_bounds__(256) void prep(const float* __restrict__ x,
                                            const float* __restrict__ wgt,
                                            unsigned short* __restrict__ xp,
                                            unsigned short* __restrict__ wt) {
    __shared__ unsigned short T[Wd * C_IN];   // used by xpose branch only
    const int bx = blockIdx.x;

    if (bx < HALO_BLKS) {
        // zero the halo ring: rows 0,57 full + cols 0,57 (h=1..56): 228 px/n
        int v = bx * 256 + threadIdx.x;       // vec8 index, 3648 per image
        int n = v / 3648, rem = v - n * 3648;
        int p = rem >> 4, c8 = rem & 15;
        int hh, ww;
        if (p < 58)       { hh = 0;       ww = p;       }
        else if (p < 116) { hh = 57;      ww = p - 58;  }
        else if (p < 172) { hh = p - 115; ww = 0;       }
        else              { hh = p - 171; ww = 57;      }
        const u16x8 z = {0, 0, 0, 0, 0, 0, 0, 0};
        *(u16x8*)(xp + ((size_t)(n * WP + hh) * WP + ww) * C_IN + c8 * 8) = z;
        return;
    }
    if (bx < HALO_BLKS + WT_BLKS) {
        // weight OIHW fp32 -> packed bf16; o = (((rs*4+ch)*2+nt)*128+n)*32+kk
        int o = (bx - HALO_BLKS) * 256 + threadIdx.x;
        int kk = o & 31, n = (o >> 5) & 127, nt = (o >> 12) & 1,
            ch = (o >> 13) & 3, rs = o >> 15;
        float v = wgt[(size_t)(nt * 128 + n) * KKTOT + (ch * 32 + kk) * 9 + rs];
        wt[o] = f2bf(v);
        return;
    }
    // x NCHW fp32 -> halo-padded NHWC bf16 (one (n,h) row per block)
    const int nb = bx - (HALO_BLKS + WT_BLKS);
    const int n = nb / Hd, h = nb - n * Hd;
    const float* src = x + (size_t)n * C_IN * HW + h * Wd;
    #pragma unroll
    for (int k = 0; k < 7; ++k) {
        int idx = threadIdx.x + k * 256;      // float4 index 0..1791
        int c = idx / 14, w4 = idx - c * 14;
        const float4 v = *(const float4*)(src + (size_t)c * HW + w4 * 4);
        const int sw = (w4 & 15) * 8;         // (w>>2)&15 == w4 for w4<=13
        T[(w4 * 4 + 0) * C_IN + (c ^ sw)] = f2bf(v.x);
        T[(w4 * 4 + 1) * C_IN + (c ^ sw)] = f2bf(v.y);
        T[(w4 * 4 + 2) * C_IN + (c ^ sw)] = f2bf(v.z);
        T[(w4 * 4 + 3) * C_IN + (c ^ sw)] = f2bf(v.w);
    }
    __syncthreads();
    unsigned short* dst = xp + ((size_t)(n * WP + h + 1) * WP + 1) * C_IN;
    const u16x8* s8 = (const u16x8*)T;
    u16x8* d8 = (u16x8*)dst;
    #pragma unroll
    for (int k = 0; k < 4; ++k) {
        int idx = threadIdx.x + k * 256;
        if (idx < 896) {
            int w = idx >> 4, j8 = idx & 15;
            d8[idx] = s8[w * 16 + (j8 ^ ((w >> 2) & 15))];
        }
    }
}

// ---- Main GEMM: A via ring-3 LDS (depth-2), B direct global->VGPR ---------
// LDS traffic halved vs prior (48 -> 24 KB/block-step): B fragments are
// loaded straight from L2-resident wt (590 KB) into registers, prefetched
// one step ahead.  Per step k (fully unrolled, constants folded):
//   barrier1                      (WAR on buf (k+2)%3 == (k-1)%3)
//   loadB(k+1) -> bf[(k+1)&1]     (4 global b128, depth-1, L2 ~200cyc)
//   issueA(k+2) -> buf (k+2)%3    (2 gld16, depth-2, HBM-tolerant)
//   s_waitcnt vmcnt(8)            (A(k) staged + B(k) in regs; leaves
//                                  A(k+1),B(k+1),A(k+2) = 8 in flight)
//   barrier2                      (A(k) visible to all waves)
//   4 ds_read_b128 (af) + 16 MFMA
__global__ __launch_bounds__(256) void conv_gemm(
    const unsigned short* __restrict__ xp, const unsigned short* __restrict__ wt,
    const float* __restrict__ bias, float* __restrict__ out)
{
    __shared__ __align__(16) unsigned short As[3][128 * 32];  // 3 x 8 KB

    const int tid = threadIdx.x;
    const int hbx = blockIdx.x;
    const int lbx = (hbx & 7) * 196 + (hbx >> 3);   // XCD-chunked, bijective
    const int nt  = lbx & 1;
    const int mtile = (lbx >> 1) * 128;

    // swizzled chunk this lane must FETCH so that slot (r, tid&3) holds it
    const int cg8 = ((tid & 3) ^ ((tid >> 3) & 3)) * 8;   // halfword offset

    const unsigned short *gA0, *gA1;
    {
        int mrow = tid >> 2;
        int m = mtile + mrow;
        int ni = m / HW; int hw = m - ni * HW; int h = hw / Wd; int w = hw - h * Wd;
        gA0 = xp + ((size_t)(ni * WP + h + 1) * WP + (w + 1)) * C_IN + cg8;
        m += 64;
        ni = m / HW; hw = m - ni * HW; h = hw / Wd; w = hw - h * Wd;
        gA1 = xp + ((size_t)(ni * WP + h + 1) * WP + (w + 1)) * C_IN + cg8;
    }

    const int wave = tid >> 6, lane = tid & 63;
    const int wrow = (wave >> 1) * 64, wcol = (wave & 1) * 64;
    const int r16 = lane & 15, quad = lane >> 4;
    const int qsw = (quad ^ ((r16 >> 1) & 3)) * 8;   // swizzled A read offset

    // B fragment base: element (((step*2+nt)*128 + wcol+ni*16+r16)*32 + quad*8)
    const unsigned short* gBf = wt + (size_t)nt * 4096 + (wcol + r16) * 32 + quad * 8;

    const f32x4 zero4 = {0.f, 0.f, 0.f, 0.f};
    f32x4 acc[4][4];
    #pragma unroll
    for (int i = 0; i < 4; ++i)
        #pragma unroll
        for (int j = 0; j < 4; ++j)
            acc[i][j] = zero4;

    bfvec8 bf[2][4];   // parity-indexed (constant after full unroll)

    auto issueA = [&](int step, int buf) {
        const int rs = step >> 2, ch = step & 3;
        const int dr = rs / 3 - 1, dc = rs % 3 - 1;
        const int aoff = (dr * WP + dc) * C_IN + ch * 32;   // wave-uniform
        gld16(gA0 + aoff, (void*)(As[buf] + tid * 8));
        gld16(gA1 + aoff, (void*)(As[buf] + 2048 + tid * 8));
    };
    auto loadB = [&](int step, int par) {
        #pragma unroll
        for (int ni = 0; ni < 4; ++ni)
            bf[par][ni] = *(const bfvec8*)(gBf + (size_t)step * 8192 + ni * 512);
    };

    // prologue: order A0, B0, A1 so waiting B0 at step 0 leaves A1 in flight
    issueA(0, 0);
    loadB(0, 0);
    issueA(1, 1);

    #pragma unroll
    for (int step = 0; step < 36; ++step) {
        const int cur = step % 3;
        const int par = step & 1;

        CFENCE(); __builtin_amdgcn_s_barrier(); CFENCE();   // WAR on (step+2)%3
        if (step < 35) loadB(step + 1, par ^ 1);
        if (step < 34) issueA(step + 2, (step + 2) % 3);
        if (step < 34) {
            asm volatile("s_waitcnt vmcnt(8)" ::: "memory");
        } else if (step == 34) {
            asm volatile("s_waitcnt vmcnt(4)" ::: "memory");
        } else {
            asm volatile("s_waitcnt vmcnt(0)" ::: "memory");
        }
        CFENCE(); __builtin_amdgcn_s_barrier(); CFENCE();   // A(step) visible

        bfvec8 af[4];
        #pragma unroll
        for (int mi = 0; mi < 4; ++mi)
            af[mi] = *(const bfvec8*)&As[cur][(wrow + mi * 16 + r16) * 32 + qsw];

        #pragma unroll
        for (int mi = 0; mi < 4; ++mi)
            #pragma unroll
            for (int ni = 0; ni < 4; ++ni)
                acc[mi][ni] = __builtin_amdgcn_mfma_f32_16x16x32_bf16(
                    af[mi], bf[par][ni], acc[mi][ni], 0, 0, 0);
    }

    // epilogue: D col=lane&15 -> k, row=quad*4+i -> m; i is m-consecutive ->
    // hwe-consecutive (3136%4==0, base%4==0) -> dwordx4 stores
    const int ntile = nt * 128;
    #pragma unroll
    for (int ni = 0; ni < 4; ++ni) {
        const int k = ntile + wcol + ni * 16 + r16;
        const float bb = bias[k];
        #pragma unroll
        for (int mi = 0; mi < 4; ++mi) {
            const int mb  = mtile + wrow + mi * 16 + quad * 4;
            const int ne  = mb / HW;
            const int hwe = mb - ne * HW;
            f32x4 v;
            #pragma unroll
            for (int i = 0; i < 4; ++i) v[i] = acc[mi][ni][i] + bb;
            *(f32x4*)(out + ((size_t)ne * K_OUT + k) * HW + hwe) = v;
        }
    }
}

extern "C" void kernel_launch(void* const* d_in, const int* in_sizes, int n_in,
                              void* d_out, int out_size, void* d_ws, size_t ws_size,
                              hipStream_t stream) {
    const float* x    = (const float*)d_in[0];
    const float* wgt  = (const float*)d_in[1];
    const float* bias = (const float*)d_in[2];
    float* out = (float*)d_out;

    unsigned short* xp = (unsigned short*)d_ws;
    unsigned short* wt = (unsigned short*)((char*)d_ws + XP_BYTES);

    prep<<<dim3(PREP_GRID), dim3(256), 0, stream>>>(x, wgt, xp, wt);
    conv_gemm<<<dim3(1568), dim3(256), 0, stream>>>(xp, wt, bias, out);
}

// Round 5
// 217.142 us; speedup vs baseline: 1.0379x; 1.0379x over previous
//
#include <hip/hip_runtime.h>

typedef __bf16 bfvec8 __attribute__((ext_vector_type(8)));
typedef float f32x4 __attribute__((ext_vector_type(4)));
typedef unsigned short u16x8 __attribute__((ext_vector_type(8)));
typedef unsigned int u32;

constexpr int C_IN = 128, Wd = 56, Hd = 56, HW = 3136, K_OUT = 256, N_IMG = 32;
constexpr int KKTOT = 1152;      // 128*9
constexpr int WP = 58;           // padded H/W
constexpr size_t XP_ELEMS = (size_t)N_IMG * WP * WP * C_IN;   // 13,776,896
constexpr size_t XP_BYTES = XP_ELEMS * 2;                     // 27,553,792
constexpr size_t WT_ELEMS = (size_t)9 * 4 * 2 * 128 * 32;     // 294,912

// prep-kernel grid partition
constexpr int HALO_BLKS = 456;    // 32 n * 228 halo px * 16 vec8 / 256 thr
constexpr int WT_BLKS   = 1152;   // 294912 / 256
constexpr int XPOSE_BLKS = N_IMG * Hd;   // 1792
constexpr int PREP_GRID = HALO_BLKS + WT_BLKS + XPOSE_BLKS;   // 3400

__device__ inline unsigned short f2bf(float f) {
    union { float f; unsigned u; } v; v.f = f;
    unsigned u = v.u;
    u += 0x7fffu + ((u >> 16) & 1u);   // round-to-nearest-even
    return (unsigned short)(u >> 16);
}

__device__ inline void gld16(const void* g, void* l) {
    __builtin_amdgcn_global_load_lds(
        (const __attribute__((address_space(1))) u32*)g,
        (__attribute__((address_space(3))) u32*)l, 16, 0, 0);
}

// compiler memory fence (no instruction) — pins LDS/global ops vs barriers
#define CFENCE() asm volatile("" ::: "memory")

// ---- Fused pre-pass: halo-zero + weight xform + NCHW->NHWC transpose ------
__global__ __launch_bounds__(256) void prep(const float* __restrict__ x,
                                            const float* __restrict__ wgt,
                                            unsigned short* __restrict__ xp,
                                            unsigned short* __restrict__ wt) {
    __shared__ unsigned short T[Wd * C_IN];   // used by xpose branch only
    const int bx = blockIdx.x;

    if (bx < HALO_BLKS) {
        // zero the halo ring: rows 0,57 full + cols 0,57 (h=1..56): 228 px/n
        int v = bx * 256 + threadIdx.x;       // vec8 index, 3648 per image
        int n = v / 3648, rem = v - n * 3648;
        int p = rem >> 4, c8 = rem & 15;
        int hh, ww;
        if (p < 58)       { hh = 0;       ww = p;       }
        else if (p < 116) { hh = 57;      ww = p - 58;  }
        else if (p < 172) { hh = p - 115; ww = 0;       }
        else              { hh = p - 171; ww = 57;      }
        const u16x8 z = {0, 0, 0, 0, 0, 0, 0, 0};
        *(u16x8*)(xp + ((size_t)(n * WP + hh) * WP + ww) * C_IN + c8 * 8) = z;
        return;
    }
    if (bx < HALO_BLKS + WT_BLKS) {
        // weight OIHW fp32 -> packed bf16; o = (((rs*4+ch)*2+nt)*128+n)*32+kk
        int o = (bx - HALO_BLKS) * 256 + threadIdx.x;
        int kk = o & 31, n = (o >> 5) & 127, nt = (o >> 12) & 1,
            ch = (o >> 13) & 3, rs = o >> 15;
        float v = wgt[(size_t)(nt * 128 + n) * KKTOT + (ch * 32 + kk) * 9 + rs];
        wt[o] = f2bf(v);
        return;
    }
    // x NCHW fp32 -> halo-padded NHWC bf16 (one (n,h) row per block)
    const int nb = bx - (HALO_BLKS + WT_BLKS);
    const int n = nb / Hd, h = nb - n * Hd;
    const float* src = x + (size_t)n * C_IN * HW + h * Wd;
    #pragma unroll
    for (int k = 0; k < 7; ++k) {
        int idx = threadIdx.x + k * 256;      // float4 index 0..1791
        int c = idx / 14, w4 = idx - c * 14;
        const float4 v = *(const float4*)(src + (size_t)c * HW + w4 * 4);
        const int sw = (w4 & 15) * 8;         // (w>>2)&15 == w4 for w4<=13
        T[(w4 * 4 + 0) * C_IN + (c ^ sw)] = f2bf(v.x);
        T[(w4 * 4 + 1) * C_IN + (c ^ sw)] = f2bf(v.y);
        T[(w4 * 4 + 2) * C_IN + (c ^ sw)] = f2bf(v.z);
        T[(w4 * 4 + 3) * C_IN + (c ^ sw)] = f2bf(v.w);
    }
    __syncthreads();
    unsigned short* dst = xp + ((size_t)(n * WP + h + 1) * WP + 1) * C_IN;
    const u16x8* s8 = (const u16x8*)T;
    u16x8* d8 = (u16x8*)dst;
    #pragma unroll
    for (int k = 0; k < 4; ++k) {
        int idx = threadIdx.x + k * 256;
        if (idx < 896) {
            int w = idx >> 4, j8 = idx & 15;
            d8[idx] = s8[w * 16 + (j8 ^ ((w >> 2) & 15))];
        }
    }
}

// ---- Main GEMM: 256x128 block, 4 waves x (128x64), ring-3 LDS, vmcnt(12) --
// Arithmetic intensity per sync doubled vs 128x128: per step a block stages
// A 16KB (4 gld16 lines) + B 8KB (2 lines) and each wave reads 12 b128 to
// feed 32 MFMA.  Ring-3 depth-2 prefetch; counted vmcnt never drains to 0.
// XCD swizzle: 784 = 8 x 98 -> each XCD's 98 blocks = 49 mtiles (~3.2 MB xp).
__global__ __launch_bounds__(256, 2) void conv_gemm(
    const unsigned short* __restrict__ xp, const unsigned short* __restrict__ wt,
    const float* __restrict__ bias, float* __restrict__ out)
{
    __shared__ __align__(16) unsigned short As[3][256 * 32];  // 3 x 16 KB
    __shared__ __align__(16) unsigned short Bs[3][128 * 32];  // 3 x  8 KB

    const int tid = threadIdx.x;
    const int hbx = blockIdx.x;
    const int lbx = (hbx & 7) * 98 + (hbx >> 3);   // XCD-chunked, bijective
    const int nt  = lbx & 1;
    const int mtile = (lbx >> 1) * 256;

    // swizzled chunk this lane must FETCH so that slot (r, tid&3) holds it
    const int cg8 = ((tid & 3) ^ ((tid >> 3) & 3)) * 8;   // halfword offset

    const unsigned short* gA[4];
    #pragma unroll
    for (int L = 0; L < 4; ++L) {
        int m = mtile + L * 64 + (tid >> 2);
        int ni = m / HW; int hw = m - ni * HW; int h = hw / Wd; int w = hw - h * Wd;
        gA[L] = xp + ((size_t)(ni * WP + h + 1) * WP + (w + 1)) * C_IN + cg8;
    }
    // wt base for this block's n-tile + this lane's row/swizzle-chunk
    const unsigned short* gB = wt + (size_t)nt * 4096 + (size_t)(tid & 0xFC) * 8 + cg8;

    const int wave = tid >> 6, lane = tid & 63;
    const int wrow = (wave >> 1) * 128, wcol = (wave & 1) * 64;
    const int r16 = lane & 15, quad = lane >> 4;
    const int qsw = (quad ^ ((r16 >> 1) & 3)) * 8;   // swizzled read offset

    const f32x4 zero4 = {0.f, 0.f, 0.f, 0.f};
    f32x4 acc[8][4];
    #pragma unroll
    for (int i = 0; i < 8; ++i)
        #pragma unroll
        for (int j = 0; j < 4; ++j)
            acc[i][j] = zero4;

    // issue the 6 staging loads for `step` into ring buffer `buf`
    auto issue = [&](int step, int buf) {
        const int rs = step >> 2, ch = step & 3;
        const int dr = rs / 3 - 1, dc = rs % 3 - 1;
        const int aoff = (dr * WP + dc) * C_IN + ch * 32;   // wave-uniform
        const size_t boff = (size_t)step * 8192;
        #pragma unroll
        for (int L = 0; L < 4; ++L)
            gld16(gA[L] + aoff, (void*)(As[buf] + L * 2048 + tid * 8));
        gld16(gB + boff,        (void*)(Bs[buf] + tid * 8));
        gld16(gB + boff + 2048, (void*)(Bs[buf] + 2048 + tid * 8));
    };

    issue(0, 0);                                  // prologue: depth-2 prefetch
    issue(1, 1);

    #pragma unroll
    for (int step = 0; step < 36; ++step) {
        const int cur = step % 3;

        CFENCE(); __builtin_amdgcn_s_barrier(); CFENCE();   // WAR on (step+2)%3
        if (step < 34) {
            issue(step + 2, (step + 2) % 3);
            asm volatile("s_waitcnt vmcnt(12)" ::: "memory");
        } else if (step == 34) {
            asm volatile("s_waitcnt vmcnt(6)" ::: "memory");
        } else {
            asm volatile("s_waitcnt vmcnt(0)" ::: "memory");
        }
        CFENCE(); __builtin_amdgcn_s_barrier(); CFENCE();   // step's loads visible

        bfvec8 bf[4];
        #pragma unroll
        for (int ni = 0; ni < 4; ++ni)
            bf[ni] = *(const bfvec8*)&Bs[cur][(wcol + ni * 16 + r16) * 32 + qsw];

        #pragma unroll
        for (int mi = 0; mi < 8; ++mi) {
            const bfvec8 af = *(const bfvec8*)&As[cur][(wrow + mi * 16 + r16) * 32 + qsw];
            #pragma unroll
            for (int ni = 0; ni < 4; ++ni)
                acc[mi][ni] = __builtin_amdgcn_mfma_f32_16x16x32_bf16(
                    af, bf[ni], acc[mi][ni], 0, 0, 0);
        }
    }

    // epilogue: D col=lane&15 -> k, row=quad*4+i -> m; i is m-consecutive ->
    // hwe-consecutive (3136%4==0, base%4==0) -> dwordx4 stores
    const int ntile = nt * 128;
    #pragma unroll
    for (int ni = 0; ni < 4; ++ni) {
        const int k = ntile + wcol + ni * 16 + r16;
        const float bb = bias[k];
        #pragma unroll
        for (int mi = 0; mi < 8; ++mi) {
            const int mb  = mtile + wrow + mi * 16 + quad * 4;
            const int ne  = mb / HW;
            const int hwe = mb - ne * HW;
            f32x4 v;
            #pragma unroll
            for (int i = 0; i < 4; ++i) v[i] = acc[mi][ni][i] + bb;
            *(f32x4*)(out + ((size_t)ne * K_OUT + k) * HW + hwe) = v;
        }
    }
}

extern "C" void kernel_launch(void* const* d_in, const int* in_sizes, int n_in,
                              void* d_out, int out_size, void* d_ws, size_t ws_size,
                              hipStream_t stream) {
    const float* x    = (const float*)d_in[0];
    const float* wgt  = (const float*)d_in[1];
    const float* bias = (const float*)d_in[2];
    float* out = (float*)d_out;

    unsigned short* xp = (unsigned short*)d_ws;
    unsigned short* wt = (unsigned short*)((char*)d_ws + XP_BYTES);

    prep<<<dim3(PREP_GRID), dim3(256), 0, stream>>>(x, wgt, xp, wt);
    conv_gemm<<<dim3(784), dim3(256), 0, stream>>>(xp, wt, bias, out);
}

// Round 6
// 214.778 us; speedup vs baseline: 1.0493x; 1.0110x over previous
//
#include <hip/hip_runtime.h>

typedef __bf16 bfvec8 __attribute__((ext_vector_type(8)));
typedef float f32x4 __attribute__((ext_vector_type(4)));
typedef unsigned short u16x8 __attribute__((ext_vector_type(8)));
typedef unsigned int u32;

constexpr int C_IN = 128, Wd = 56, Hd = 56, HW = 3136, K_OUT = 256, N_IMG = 32;
constexpr int KKTOT = 1152;      // 128*9
constexpr int WP = 58;           // padded H/W
constexpr size_t XP_ELEMS = (size_t)N_IMG * WP * WP * C_IN;   // 13,776,896
constexpr size_t XP_BYTES = XP_ELEMS * 2;                     // 27,553,792
constexpr size_t WT_ELEMS = (size_t)9 * 4 * 2 * 128 * 32;     // 294,912

// prep-kernel grid partition
constexpr int HALO_BLKS = 456;    // 32 n * 228 halo px * 16 vec8 / 256 thr
constexpr int WT_BLKS   = 1152;   // 294912 / 256
constexpr int XPOSE_BLKS = N_IMG * Hd;   // 1792
constexpr int PREP_GRID = HALO_BLKS + WT_BLKS + XPOSE_BLKS;   // 3400

__device__ inline unsigned short f2bf(float f) {
    union { float f; unsigned u; } v; v.f = f;
    unsigned u = v.u;
    u += 0x7fffu + ((u >> 16) & 1u);   // round-to-nearest-even
    return (unsigned short)(u >> 16);
}

__device__ inline void gld16(const void* g, void* l) {
    __builtin_amdgcn_global_load_lds(
        (const __attribute__((address_space(1))) u32*)g,
        (__attribute__((address_space(3))) u32*)l, 16, 0, 0);
}

// compiler memory fence (no instruction) — pins LDS/global ops vs barriers
#define CFENCE() asm volatile("" ::: "memory")

// ---- Fused pre-pass: halo-zero + weight xform + NCHW->NHWC transpose ------
__global__ __launch_bounds__(256) void prep(const float* __restrict__ x,
                                            const float* __restrict__ wgt,
                                            unsigned short* __restrict__ xp,
                                            unsigned short* __restrict__ wt) {
    __shared__ unsigned short T[Wd * C_IN];   // used by xpose branch only
    const int bx = blockIdx.x;

    if (bx < HALO_BLKS) {
        // zero the halo ring: rows 0,57 full + cols 0,57 (h=1..56): 228 px/n
        int v = bx * 256 + threadIdx.x;       // vec8 index, 3648 per image
        int n = v / 3648, rem = v - n * 3648;
        int p = rem >> 4, c8 = rem & 15;
        int hh, ww;
        if (p < 58)       { hh = 0;       ww = p;       }
        else if (p < 116) { hh = 57;      ww = p - 58;  }
        else if (p < 172) { hh = p - 115; ww = 0;       }
        else              { hh = p - 171; ww = 57;      }
        const u16x8 z = {0, 0, 0, 0, 0, 0, 0, 0};
        *(u16x8*)(xp + ((size_t)(n * WP + hh) * WP + ww) * C_IN + c8 * 8) = z;
        return;
    }
    if (bx < HALO_BLKS + WT_BLKS) {
        // weight OIHW fp32 -> packed bf16; o = (((rs*4+ch)*2+nt)*128+n)*32+kk
        int o = (bx - HALO_BLKS) * 256 + threadIdx.x;
        int kk = o & 31, n = (o >> 5) & 127, nt = (o >> 12) & 1,
            ch = (o >> 13) & 3, rs = o >> 15;
        float v = wgt[(size_t)(nt * 128 + n) * KKTOT + (ch * 32 + kk) * 9 + rs];
        wt[o] = f2bf(v);
        return;
    }
    // x NCHW fp32 -> halo-padded NHWC bf16 (one (n,h) row per block)
    const int nb = bx - (HALO_BLKS + WT_BLKS);
    const int n = nb / Hd, h = nb - n * Hd;
    const float* src = x + (size_t)n * C_IN * HW + h * Wd;
    #pragma unroll
    for (int k = 0; k < 7; ++k) {
        int idx = threadIdx.x + k * 256;      // float4 index 0..1791
        int c = idx / 14, w4 = idx - c * 14;
        const float4 v = *(const float4*)(src + (size_t)c * HW + w4 * 4);
        const int sw = (w4 & 15) * 8;         // (w>>2)&15 == w4 for w4<=13
        T[(w4 * 4 + 0) * C_IN + (c ^ sw)] = f2bf(v.x);
        T[(w4 * 4 + 1) * C_IN + (c ^ sw)] = f2bf(v.y);
        T[(w4 * 4 + 2) * C_IN + (c ^ sw)] = f2bf(v.z);
        T[(w4 * 4 + 3) * C_IN + (c ^ sw)] = f2bf(v.w);
    }
    __syncthreads();
    unsigned short* dst = xp + ((size_t)(n * WP + h + 1) * WP + 1) * C_IN;
    const u16x8* s8 = (const u16x8*)T;
    u16x8* d8 = (u16x8*)dst;
    #pragma unroll
    for (int k = 0; k < 4; ++k) {
        int idx = threadIdx.x + k * 256;
        if (idx < 896) {
            int w = idx >> 4, j8 = idx & 15;
            d8[idx] = s8[w * 16 + (j8 ^ ((w >> 2) & 15))];
        }
    }
}

// ---- Main GEMM: R3 skeleton (128x128, ring-3, 3-resident) + reg-level -----
// fragment double-buffering.  vmcnt(4) after barrier2(k) makes BOTH step k
// and k+1 LDS buffers all-wave valid (each wave waited on its own k+1 lines
// pre-barrier), so region k prefetches frags(k+1) into the alternate register
// set while MFMA(k) runs from registers loaded last region.  MFMA starts
// immediately post-barrier; the 8 ds_read_b128 get a whole region of slack.
// WAR: frags(b) read in region b-1, consumed by MFMA(b) (lgkmcnt-forced
// completion) before barrier1(b+1) re-issues buf b.  T5 setprio on MFMA.
__global__ __launch_bounds__(256, 3) void conv_gemm(
    const unsigned short* __restrict__ xp, const unsigned short* __restrict__ wt,
    const float* __restrict__ bias, float* __restrict__ out)
{
    __shared__ __align__(16) unsigned short As[3][128 * 32];  // 3 x 8 KB
    __shared__ __align__(16) unsigned short Bs[3][128 * 32];  // 3 x 8 KB

    const int tid = threadIdx.x;
    const int hbx = blockIdx.x;
    const int lbx = (hbx & 7) * 196 + (hbx >> 3);   // XCD-chunked, bijective
    const int nt  = lbx & 1;
    const int mtile = (lbx >> 1) * 128;

    // swizzled chunk this lane must FETCH so that slot (r, tid&3) holds it
    const int cg8 = ((tid & 3) ^ ((tid >> 3) & 3)) * 8;   // halfword offset

    const unsigned short *gA0, *gA1;
    {
        int mrow = tid >> 2;
        int m = mtile + mrow;
        int ni = m / HW; int hw = m - ni * HW; int h = hw / Wd; int w = hw - h * Wd;
        gA0 = xp + ((size_t)(ni * WP + h + 1) * WP + (w + 1)) * C_IN + cg8;
        m += 64;
        ni = m / HW; hw = m - ni * HW; h = hw / Wd; w = hw - h * Wd;
        gA1 = xp + ((size_t)(ni * WP + h + 1) * WP + (w + 1)) * C_IN + cg8;
    }
    // wt base for this block's n-tile + this lane's row/swizzle-chunk
    const unsigned short* gB = wt + (size_t)nt * 4096 + (size_t)(tid & 0xFC) * 8 + cg8;

    const int wave = tid >> 6, lane = tid & 63;
    const int wrow = (wave >> 1) * 64, wcol = (wave & 1) * 64;
    const int r16 = lane & 15, quad = lane >> 4;
    const int qsw = (quad ^ ((r16 >> 1) & 3)) * 8;   // swizzled read offset

    const f32x4 zero4 = {0.f, 0.f, 0.f, 0.f};
    f32x4 acc[4][4];
    #pragma unroll
    for (int i = 0; i < 4; ++i)
        #pragma unroll
        for (int j = 0; j < 4; ++j)
            acc[i][j] = zero4;

    bfvec8 af[2][4], bf[2][4];   // parity sets; indices constant after unroll

    auto issue = [&](int step, int buf) {
        const int rs = step >> 2, ch = step & 3;
        const int dr = rs / 3 - 1, dc = rs % 3 - 1;
        const int aoff = (dr * WP + dc) * C_IN + ch * 32;   // wave-uniform
        const size_t boff = (size_t)step * 8192;
        gld16(gA0 + aoff, (void*)(As[buf] + tid * 8));
        gld16(gA1 + aoff, (void*)(As[buf] + 2048 + tid * 8));
        gld16(gB + boff,        (void*)(Bs[buf] + tid * 8));
        gld16(gB + boff + 2048, (void*)(Bs[buf] + 2048 + tid * 8));
    };
    auto readFrags = [&](int step, int set) {
        const int cur = step % 3;
        #pragma unroll
        for (int mi = 0; mi < 4; ++mi)
            af[set][mi] = *(const bfvec8*)&As[cur][(wrow + mi * 16 + r16) * 32 + qsw];
        #pragma unroll
        for (int ni = 0; ni < 4; ++ni)
            bf[set][ni] = *(const bfvec8*)&Bs[cur][(wcol + ni * 16 + r16) * 32 + qsw];
    };

    // prologue: depth-2 staging; land step 0; preload frags(0) into set 0
    issue(0, 0);
    issue(1, 1);
    asm volatile("s_waitcnt vmcnt(4)" ::: "memory");        // step-0 lines landed
    CFENCE(); __builtin_amdgcn_s_barrier(); CFENCE();       // ...for all waves
    readFrags(0, 0);

    #pragma unroll
    for (int step = 0; step < 36; ++step) {
        const int par = step & 1;

        CFENCE(); __builtin_amdgcn_s_barrier(); CFENCE();   // WAR on (step+2)%3
        if (step < 34) {
            issue(step + 2, (step + 2) % 3);
            asm volatile("s_waitcnt vmcnt(4)" ::: "memory");  // step+1 landed
        } else if (step == 34) {
            asm volatile("s_waitcnt vmcnt(0)" ::: "memory");  // step 35 landed
        }
        CFENCE(); __builtin_amdgcn_s_barrier(); CFENCE();   // step+1 visible to all

        if (step < 35) readFrags(step + 1, par ^ 1);        // prefetch next frags

        __builtin_amdgcn_s_setprio(1);
        #pragma unroll
        for (int mi = 0; mi < 4; ++mi)
            #pragma unroll
            for (int ni = 0; ni < 4; ++ni)
                acc[mi][ni] = __builtin_amdgcn_mfma_f32_16x16x32_bf16(
                    af[par][mi], bf[par][ni], acc[mi][ni], 0, 0, 0);
        __builtin_amdgcn_s_setprio(0);
    }

    // epilogue: D col=lane&15 -> k, row=quad*4+i -> m; i is m-consecutive ->
    // hwe-consecutive (3136%4==0, base%4==0) -> dwordx4 stores
    const int ntile = nt * 128;
    #pragma unroll
    for (int ni = 0; ni < 4; ++ni) {
        const int k = ntile + wcol + ni * 16 + r16;
        const float bb = bias[k];
        #pragma unroll
        for (int mi = 0; mi < 4; ++mi) {
            const int mb  = mtile + wrow + mi * 16 + quad * 4;
            const int ne  = mb / HW;
            const int hwe = mb - ne * HW;
            f32x4 v;
            #pragma unroll
            for (int i = 0; i < 4; ++i) v[i] = acc[mi][ni][i] + bb;
            *(f32x4*)(out + ((size_t)ne * K_OUT + k) * HW + hwe) = v;
        }
    }
}

extern "C" void kernel_launch(void* const* d_in, const int* in_sizes, int n_in,
                              void* d_out, int out_size, void* d_ws, size_t ws_size,
                              hipStream_t stream) {
    const float* x    = (const float*)d_in[0];
    const float* wgt  = (const float*)d_in[1];
    const float* bias = (const float*)d_in[2];
    float* out = (float*)d_out;

    unsigned short* xp = (unsigned short*)d_ws;
    unsigned short* wt = (unsigned short*)((char*)d_ws + XP_BYTES);

    prep<<<dim3(PREP_GRID), dim3(256), 0, stream>>>(x, wgt, xp, wt);
    conv_gemm<<<dim3(1568), dim3(256), 0, stream>>>(xp, wt, bias, out);
}

// Round 7
// 212.576 us; speedup vs baseline: 1.0602x; 1.0104x over previous
//
#include <hip/hip_runtime.h>

typedef __bf16 bfvec8 __attribute__((ext_vector_type(8)));
typedef float f32x4 __attribute__((ext_vector_type(4)));
typedef unsigned short u16x8 __attribute__((ext_vector_type(8)));
typedef unsigned int u32;

constexpr int C_IN = 128, Wd = 56, Hd = 56, HW = 3136, K_OUT = 256, N_IMG = 32;
constexpr int KKTOT = 1152;      // 128*9
constexpr int WP = 58;           // padded H/W
constexpr size_t XP_ELEMS = (size_t)N_IMG * WP * WP * C_IN;   // 13,776,896
constexpr size_t XP_BYTES = XP_ELEMS * 2;                     // 27,553,792
constexpr size_t WT_ELEMS = (size_t)9 * 4 * 2 * 128 * 32;     // 294,912

// prep-kernel grid partition
constexpr int HALO_BLKS = 456;    // 32 n * 228 halo px * 16 vec8 / 256 thr
constexpr int WT_BLKS   = 1152;   // 294912 / 256
constexpr int XPOSE_BLKS = N_IMG * Hd;   // 1792
constexpr int PREP_GRID = HALO_BLKS + WT_BLKS + XPOSE_BLKS;   // 3400

__device__ inline unsigned short f2bf(float f) {
    union { float f; unsigned u; } v; v.f = f;
    unsigned u = v.u;
    u += 0x7fffu + ((u >> 16) & 1u);   // round-to-nearest-even
    return (unsigned short)(u >> 16);
}

__device__ inline void gld16(const void* g, void* l) {
    __builtin_amdgcn_global_load_lds(
        (const __attribute__((address_space(1))) u32*)g,
        (__attribute__((address_space(3))) u32*)l, 16, 0, 0);
}

// compiler memory fence (no instruction) — pins LDS/global ops vs barriers
#define CFENCE() asm volatile("" ::: "memory")

// ---- Fused pre-pass: halo-zero + weight xform + NCHW->NHWC transpose ------
__global__ __launch_bounds__(256) void prep(const float* __restrict__ x,
                                            const float* __restrict__ wgt,
                                            unsigned short* __restrict__ xp,
                                            unsigned short* __restrict__ wt) {
    __shared__ unsigned short T[Wd * C_IN];   // used by xpose branch only
    const int bx = blockIdx.x;

    if (bx < HALO_BLKS) {
        // zero the halo ring: rows 0,57 full + cols 0,57 (h=1..56): 228 px/n
        int v = bx * 256 + threadIdx.x;       // vec8 index, 3648 per image
        int n = v / 3648, rem = v - n * 3648;
        int p = rem >> 4, c8 = rem & 15;
        int hh, ww;
        if (p < 58)       { hh = 0;       ww = p;       }
        else if (p < 116) { hh = 57;      ww = p - 58;  }
        else if (p < 172) { hh = p - 115; ww = 0;       }
        else              { hh = p - 171; ww = 57;      }
        const u16x8 z = {0, 0, 0, 0, 0, 0, 0, 0};
        *(u16x8*)(xp + ((size_t)(n * WP + hh) * WP + ww) * C_IN + c8 * 8) = z;
        return;
    }
    if (bx < HALO_BLKS + WT_BLKS) {
        // weight OIHW fp32 -> packed bf16; o = (((rs*4+ch)*2+nt)*128+n)*32+kk
        int o = (bx - HALO_BLKS) * 256 + threadIdx.x;
        int kk = o & 31, n = (o >> 5) & 127, nt = (o >> 12) & 1,
            ch = (o >> 13) & 3, rs = o >> 15;
        float v = wgt[(size_t)(nt * 128 + n) * KKTOT + (ch * 32 + kk) * 9 + rs];
        wt[o] = f2bf(v);
        return;
    }
    // x NCHW fp32 -> halo-padded NHWC bf16 (one (n,h) row per block)
    const int nb = bx - (HALO_BLKS + WT_BLKS);
    const int n = nb / Hd, h = nb - n * Hd;
    const float* src = x + (size_t)n * C_IN * HW + h * Wd;
    #pragma unroll
    for (int k = 0; k < 7; ++k) {
        int idx = threadIdx.x + k * 256;      // float4 index 0..1791
        int c = idx / 14, w4 = idx - c * 14;
        const float4 v = *(const float4*)(src + (size_t)c * HW + w4 * 4);
        const int sw = (w4 & 15) * 8;         // (w>>2)&15 == w4 for w4<=13
        T[(w4 * 4 + 0) * C_IN + (c ^ sw)] = f2bf(v.x);
        T[(w4 * 4 + 1) * C_IN + (c ^ sw)] = f2bf(v.y);
        T[(w4 * 4 + 2) * C_IN + (c ^ sw)] = f2bf(v.z);
        T[(w4 * 4 + 3) * C_IN + (c ^ sw)] = f2bf(v.w);
    }
    __syncthreads();
    unsigned short* dst = xp + ((size_t)(n * WP + h + 1) * WP + 1) * C_IN;
    const u16x8* s8 = (const u16x8*)T;
    u16x8* d8 = (u16x8*)dst;
    #pragma unroll
    for (int k = 0; k < 4; ++k) {
        int idx = threadIdx.x + k * 256;
        if (idx < 896) {
            int w = idx >> 4, j8 = idx & 15;
            d8[idx] = s8[w * 16 + (j8 ^ ((w >> 2) & 15))];
        }
    }
}

// ---- Main GEMM: exact R3 structure (83.7 us) ------------------------------
// ring-3 LDS, depth-2 prefetch, counted vmcnt(8), XCD-chunked swizzle.
// Fully unrolled 36-step loop.  Per step k:
//   barrier                          (WAR: buf (k-1)%3 reads complete)
//   issue step k+2 into buf (k+2)%3
//   s_waitcnt vmcnt(8)               (step k's 4 loads landed; 8 in flight)
//   barrier                          (all waves' step-k loads visible)
//   8 ds_read_b128 + 16 MFMA from buf k%3
__global__ __launch_bounds__(256) void conv_gemm(
    const unsigned short* __restrict__ xp, const unsigned short* __restrict__ wt,
    const float* __restrict__ bias, float* __restrict__ out)
{
    __shared__ __align__(16) unsigned short As[3][128 * 32];  // 3 x 8 KB
    __shared__ __align__(16) unsigned short Bs[3][128 * 32];  // 3 x 8 KB

    const int tid = threadIdx.x;
    const int hbx = blockIdx.x;
    const int lbx = (hbx & 7) * 196 + (hbx >> 3);   // XCD-chunked, bijective
    const int nt  = lbx & 1;
    const int mtile = (lbx >> 1) * 128;

    // swizzled chunk this lane must FETCH so that slot (r, tid&3) holds it
    const int cg8 = ((tid & 3) ^ ((tid >> 3) & 3)) * 8;   // halfword offset

    const unsigned short *gA0, *gA1;
    {
        int mrow = tid >> 2;
        int m = mtile + mrow;
        int ni = m / HW; int hw = m - ni * HW; int h = hw / Wd; int w = hw - h * Wd;
        gA0 = xp + ((size_t)(ni * WP + h + 1) * WP + (w + 1)) * C_IN + cg8;
        m += 64;
        ni = m / HW; hw = m - ni * HW; h = hw / Wd; w = hw - h * Wd;
        gA1 = xp + ((size_t)(ni * WP + h + 1) * WP + (w + 1)) * C_IN + cg8;
    }
    // wt base for this block's n-tile + this lane's row/swizzle-chunk
    const unsigned short* gB = wt + (size_t)nt * 4096 + (size_t)(tid & 0xFC) * 8 + cg8;

    const int wave = tid >> 6, lane = tid & 63;
    const int wrow = (wave >> 1) * 64, wcol = (wave & 1) * 64;
    const int r16 = lane & 15, quad = lane >> 4;
    const int qsw = (quad ^ ((r16 >> 1) & 3)) * 8;   // swizzled read offset

    const f32x4 zero4 = {0.f, 0.f, 0.f, 0.f};
    f32x4 acc[4][4];
    #pragma unroll
    for (int i = 0; i < 4; ++i)
        #pragma unroll
        for (int j = 0; j < 4; ++j)
            acc[i][j] = zero4;

    // issue the 4 staging loads for `step` into ring buffer `buf`
    auto issue = [&](int step, int buf) {
        const int rs = step >> 2, ch = step & 3;
        const int dr = rs / 3 - 1, dc = rs % 3 - 1;
        const int aoff = (dr * WP + dc) * C_IN + ch * 32;   // wave-uniform
        const size_t boff = (size_t)step * 8192;
        gld16(gA0 + aoff, (void*)(As[buf] + tid * 8));
        gld16(gA1 + aoff, (void*)(As[buf] + 2048 + tid * 8));
        gld16(gB + boff,        (void*)(Bs[buf] + tid * 8));
        gld16(gB + boff + 2048, (void*)(Bs[buf] + 2048 + tid * 8));
    };

    issue(0, 0);                                  // prologue: depth-2 prefetch
    issue(1, 1);

    #pragma unroll
    for (int step = 0; step < 36; ++step) {
        const int cur = step % 3;

        CFENCE(); __builtin_amdgcn_s_barrier(); CFENCE();   // WAR on (step+2)%3
        if (step < 34) {
            issue(step + 2, (step + 2) % 3);
            asm volatile("s_waitcnt vmcnt(8)" ::: "memory");
        } else if (step == 34) {
            asm volatile("s_waitcnt vmcnt(4)" ::: "memory");
        } else {
            asm volatile("s_waitcnt vmcnt(0)" ::: "memory");
        }
        CFENCE(); __builtin_amdgcn_s_barrier(); CFENCE();   // step's loads visible

        bfvec8 af[4], bf[4];
        #pragma unroll
        for (int mi = 0; mi < 4; ++mi)
            af[mi] = *(const bfvec8*)&As[cur][(wrow + mi * 16 + r16) * 32 + qsw];
        #pragma unroll
        for (int ni = 0; ni < 4; ++ni)
            bf[ni] = *(const bfvec8*)&Bs[cur][(wcol + ni * 16 + r16) * 32 + qsw];

        #pragma unroll
        for (int mi = 0; mi < 4; ++mi)
            #pragma unroll
            for (int ni = 0; ni < 4; ++ni)
                acc[mi][ni] = __builtin_amdgcn_mfma_f32_16x16x32_bf16(
                    af[mi], bf[ni], acc[mi][ni], 0, 0, 0);
    }

    // epilogue: D col=lane&15 -> k, row=quad*4+i -> m; i is m-consecutive ->
    // hwe-consecutive (3136%4==0, base%4==0) -> dwordx4 stores
    const int ntile = nt * 128;
    #pragma unroll
    for (int ni = 0; ni < 4; ++ni) {
        const int k = ntile + wcol + ni * 16 + r16;
        const float bb = bias[k];
        #pragma unroll
        for (int mi = 0; mi < 4; ++mi) {
            const int mb  = mtile + wrow + mi * 16 + quad * 4;
            const int ne  = mb / HW;
            const int hwe = mb - ne * HW;
            f32x4 v;
            #pragma unroll
            for (int i = 0; i < 4; ++i) v[i] = acc[mi][ni][i] + bb;
            *(f32x4*)(out + ((size_t)ne * K_OUT + k) * HW + hwe) = v;
        }
    }
}

extern "C" void kernel_launch(void* const* d_in, const int* in_sizes, int n_in,
                              void* d_out, int out_size, void* d_ws, size_t ws_size,
                              hipStream_t stream) {
    const float* x    = (const float*)d_in[0];
    const float* wgt  = (const float*)d_in[1];
    const float* bias = (const float*)d_in[2];
    float* out = (float*)d_out;

    unsigned short* xp = (unsigned short*)d_ws;
    unsigned short* wt = (unsigned short*)((char*)d_ws + XP_BYTES);

    prep<<<dim3(PREP_GRID), dim3(256), 0, stream>>>(x, wgt, xp, wt);
    conv_gemm<<<dim3(1568), dim3(256), 0, stream>>>(xp, wt, bias, out);
}